// Round 9
// baseline (435.798 us; speedup 1.0000x reference)
//
#include <hip/hip_runtime.h>
#include <hip/hip_bf16.h>
#include <hip/hip_fp16.h>

// SparseGAT forward. fp16-MFMA feature transform (128-row tile, wave-per-head,
// fused transpose + aw); CSR edge pipeline, 16-lane-group rows assigned in
// DEGREE-SORTED order (kills intra-wave trip-count divergence).
// N=50000, FI=256, FO=64, H=8, E=800000, avg deg 16.
//
// Th2 [n][f*8+h] head-minor fp16 (1KB/row).
// ws: Th2[N*512]f16 | Wth[8*64*256]f16 | aw[N*8]f32 | deg[N] | degcnt[64]
//     | row_start[N+4] | cursor[N] | colperm[E] | blocksums[64] | degoff[64]
//     | row_order[N]

#define FI 256
#define FO 64
#define NH 8
#define FC 512
#define BM 128
#define NBIN 64

typedef _Float16 f16x8 __attribute__((ext_vector_type(8)));
typedef float f32x16 __attribute__((ext_vector_type(16)));
typedef float f32x8 __attribute__((ext_vector_type(8)));

// ---------------- P1: W[h][k][f] -> Wth[h][f][k] fp16 -----------------------
__global__ __launch_bounds__(256)
void p1_wconv(const float* __restrict__ W, _Float16* __restrict__ Wth) {
  int idx = blockIdx.x * 256 + threadIdx.x;   // h*64*256 + f*256 + k
  if (idx >= NH * FO * FI) return;
  int k = idx & (FI - 1);
  int f = (idx >> 8) & (FO - 1);
  int h = idx >> 14;
  Wth[idx] = (_Float16)W[((size_t)h * FI + k) * FO + f];
}

// ---------------- K1v2: 128-row tile, wave = head ---------------------------
__global__ __launch_bounds__(512)
void k1_v2(const float* __restrict__ x, const _Float16* __restrict__ Wth,
           const float* __restrict__ a, _Float16* __restrict__ Th2,
           float* __restrict__ aw, int N) {
  __shared__ _Float16 smem[BM * 136];            // 34.8 KB, aliased Xs / Tt
  auto Xs = reinterpret_cast<_Float16(*)[136]>(smem);   // [128][136]
  auto Tt = reinterpret_cast<_Float16(*)[512]>(smem);   // [32][512]
  const int bm = blockIdx.x * BM;
  const int t = threadIdx.x;
  const int w = t >> 6;             // wave id = head
  const int lane = t & 63;
  const int l31 = lane & 31;
  const int kh = (lane >> 5) * 8;
  const _Float16* Wh = Wth + (size_t)w * (FO * FI);

  f32x16 acc[4][2];
  #pragma unroll
  for (int mr = 0; mr < 4; ++mr)
    #pragma unroll
    for (int wc = 0; wc < 2; ++wc) acc[mr][wc] = (f32x16)0.0f;

  #pragma unroll
  for (int k0 = 0; k0 < 2; ++k0) {
    if (k0) __syncthreads();
    #pragma unroll
    for (int r = 0; r < 8; ++r) {
      int i = t + r * 512;          // 0..4095
      int row = i >> 5;             // 32 float4 per row
      int q = i & 31;
      float4 v = make_float4(0.f, 0.f, 0.f, 0.f);
      if (bm + row < N)
        v = reinterpret_cast<const float4*>(&x[(size_t)(bm + row) * FI + k0 * 128])[q];
      _Float16 o[4] = {(_Float16)v.x, (_Float16)v.y, (_Float16)v.z, (_Float16)v.w};
      *reinterpret_cast<uint2*>(&Xs[row][q * 4]) = *reinterpret_cast<uint2*>(o);
    }
    __syncthreads();
    #pragma unroll
    for (int kk = 0; kk < 8; ++kk) {
      f16x8 af[4], bf[2];
      #pragma unroll
      for (int mr = 0; mr < 4; ++mr)
        af[mr] = *reinterpret_cast<const f16x8*>(&Xs[mr * 32 + l31][kk * 16 + kh]);
      #pragma unroll
      for (int wc = 0; wc < 2; ++wc)
        bf[wc] = *reinterpret_cast<const f16x8*>(
            &Wh[(size_t)(wc * 32 + l31) * FI + k0 * 128 + kk * 16 + kh]);
      #pragma unroll
      for (int mr = 0; mr < 4; ++mr)
        #pragma unroll
        for (int wc = 0; wc < 2; ++wc)
          acc[mr][wc] =
              __builtin_amdgcn_mfma_f32_32x32x16_f16(af[mr], bf[wc], acc[mr][wc], 0, 0, 0);
    }
  }

  // aw[n][w] = sum_f T[n][w][f] * a[w][f]
  const float av0 = a[w * FO + l31], av1 = a[w * FO + 32 + l31];
  #pragma unroll
  for (int mr = 0; mr < 4; ++mr)
    #pragma unroll
    for (int reg = 0; reg < 16; ++reg) {
      float s = acc[mr][0][reg] * av0 + acc[mr][1][reg] * av1;
      #pragma unroll
      for (int off = 1; off < 32; off <<= 1) s += __shfl_xor(s, off);
      if (l31 == 0) {
        int rl = mr * 32 + (reg & 3) + 8 * (reg >> 2) + 4 * (lane >> 5);
        if (bm + rl < N) aw[(size_t)(bm + rl) * NH + w] = s;
      }
    }

  // Th2: transpose 32-row chunks through LDS, coalesced 16B stores
  #pragma unroll
  for (int ch = 0; ch < 4; ++ch) {
    __syncthreads();
    #pragma unroll
    for (int wc = 0; wc < 2; ++wc) {
      const int f = wc * 32 + l31;
      #pragma unroll
      for (int reg = 0; reg < 16; ++reg) {
        int rl = (reg & 3) + 8 * (reg >> 2) + 4 * (lane >> 5);
        Tt[rl][f * NH + w] = (_Float16)acc[ch][wc][reg];
      }
    }
    __syncthreads();
    #pragma unroll
    for (int r = 0; r < 4; ++r) {
      int i = t + r * 512;          // 0..2047
      int row = i >> 6, q = i & 63;
      int grow = bm + ch * 32 + row;
      if (grow < N)
        *reinterpret_cast<uint4*>(&Th2[(size_t)grow * FC + q * 8]) =
            *reinterpret_cast<const uint4*>(&Tt[row][q * 8]);
    }
  }
}

// ---------------- B1: degree histogram --------------------------------------
__global__ __launch_bounds__(256)
void b1_hist(const int* __restrict__ rows, int* __restrict__ deg, int E) {
  int e = blockIdx.x * 256 + threadIdx.x;
  if (e < E) atomicAdd(&deg[rows[e]], 1);
}

// ---------------- B2a: per-block sums (1024 elems/block) --------------------
__global__ __launch_bounds__(256)
void b2a_blocksum(const int* __restrict__ deg, int* __restrict__ blocksums, int N) {
  __shared__ int red[256];
  const int t = threadIdx.x;
  const int base = blockIdx.x * 1024 + t * 4;
  int s = 0;
  #pragma unroll
  for (int j = 0; j < 4; ++j) { int i = base + j; if (i < N) s += deg[i]; }
  red[t] = s;
  __syncthreads();
  for (int off = 128; off; off >>= 1) {
    if (t < off) red[t] += red[t + off];
    __syncthreads();
  }
  if (t == 0) blocksums[blockIdx.x] = red[0];
}

// ---------------- B2b: exclusive scan of block sums (1 wave) ----------------
__global__ __launch_bounds__(64)
void b2b_scanblocks(int* __restrict__ blocksums, int nb,
                    int* __restrict__ row_start, int N, int E) {
  const int lane = threadIdx.x;
  int carry = 0;
  for (int base = 0; base < nb; base += 64) {
    int i = base + lane;
    int v = (i < nb) ? blocksums[i] : 0;
    int inc = v;
    #pragma unroll
    for (int off = 1; off < 64; off <<= 1) {
      int t = __shfl_up(inc, off);
      if (lane >= off) inc += t;
    }
    if (i < nb) blocksums[i] = inc - v + carry;  // exclusive
    carry += __shfl(inc, 63);
  }
  if (lane == 0) row_start[N] = E;
}

// ---------------- B2c: per-block rescan -> row_start, cursor; + deg hist ----
__global__ __launch_bounds__(256)
void b2c_rescan(const int* __restrict__ deg, const int* __restrict__ blocksums,
                int* __restrict__ row_start, int* __restrict__ cursor,
                int* __restrict__ degcnt, int N) {
  __shared__ int ts[256];
  __shared__ int hist[NBIN];
  const int t = threadIdx.x;
  const int base = blockIdx.x * 1024 + t * 4;
  if (t < NBIN) hist[t] = 0;
  int v[4]; int s = 0;
  #pragma unroll
  for (int j = 0; j < 4; ++j) { int i = base + j; v[j] = (i < N) ? deg[i] : 0; s += v[j]; }
  ts[t] = s;
  __syncthreads();
  for (int off = 1; off < 256; off <<= 1) {
    int add = (t >= off) ? ts[t - off] : 0;
    __syncthreads();
    ts[t] += add;
    __syncthreads();
  }
  int run = blocksums[blockIdx.x] + ts[t] - s;
  #pragma unroll
  for (int j = 0; j < 4; ++j) {
    int i = base + j;
    if (i < N) {
      row_start[i] = run; cursor[i] = run; run += v[j];
      atomicAdd(&hist[min(v[j], NBIN - 1)], 1);
    }
  }
  __syncthreads();
  if (t < NBIN && hist[t]) atomicAdd(&degcnt[t], hist[t]);
}

// ---------------- B3: scatter cols into CSR order ---------------------------
__global__ __launch_bounds__(256)
void b3_scatter(const int* __restrict__ rows, const int* __restrict__ cols,
                int* __restrict__ cursor, int* __restrict__ colperm, int E) {
  int e = blockIdx.x * 256 + threadIdx.x;
  if (e >= E) return;
  int pos = atomicAdd(&cursor[rows[e]], 1);
  colperm[pos] = cols[e];
}

// ---------------- B4: exclusive scan of 64 degree bins (1 wave) -------------
__global__ __launch_bounds__(64)
void b4_degscan(const int* __restrict__ degcnt, int* __restrict__ degoff) {
  const int lane = threadIdx.x;
  int v = degcnt[lane];
  int inc = v;
  #pragma unroll
  for (int off = 1; off < 64; off <<= 1) {
    int t = __shfl_up(inc, off);
    if (lane >= off) inc += t;
  }
  degoff[lane] = inc - v;   // exclusive
}

// ---------------- B5: scatter rows into degree-sorted order -----------------
__global__ __launch_bounds__(256)
void b5_roworder(const int* __restrict__ deg, int* __restrict__ degoff,
                 int* __restrict__ row_order, int N) {
  int i = blockIdx.x * 256 + threadIdx.x;
  if (i >= N) return;
  int pos = atomicAdd(&degoff[min(deg[i], NBIN - 1)], 1);
  row_order[pos] = i;
}

// ---------------- K4: fused softmax + aggregation, row per 16-lane group ----
// Rows assigned in degree-sorted order: groups in a wave have equal degree,
// so the lockstep loop has no masked-off iterations.
__global__ __launch_bounds__(256)
void k4_fused(const int* __restrict__ row_start, const int* __restrict__ colperm,
              const int* __restrict__ row_order,
              const float* __restrict__ aw, const _Float16* __restrict__ Th2,
              const float* __restrict__ b, float* __restrict__ out, int N) {
  const int lane16 = threadIdx.x & 15;
  const int gbase  = threadIdx.x & 48;       // group base lane within wave
  const int ri = blockIdx.x * 16 + (threadIdx.x >> 4);
  if (ri >= N) return;
  const int r = row_order[ri];

  const int s0 = row_start[r], s1 = row_start[r + 1];
  f32x8 awr = *reinterpret_cast<const f32x8*>(&aw[(size_t)r * NH]);

  float facc[4][NH] = {};
  float dacc[NH] = {};

  for (int base = s0; base < s1; base += 16) {
    const int mm = min(16, s1 - base);
    const bool valid = lane16 < mm;
    int c_l = valid ? colperm[base + lane16] : 0;

    // lane-parallel ex over this group's <=16 edges
    f32x8 awc = *reinterpret_cast<const f32x8*>(&aw[(size_t)c_l * NH]);
    float ex[NH];
    #pragma unroll
    for (int h = 0; h < NH; ++h) {
      float s = awr[h] + awc[h];
      float lr = s > 0.f ? s : 0.2f * s;
      ex[h] = valid ? __expf(lr) : 0.f;
      dacc[h] += ex[h];
    }

    // serial gather: per edge, 4 independent quarter-row loads
    for (int j = 0; j < mm; ++j) {
      int cj = __shfl(c_l, gbase + j);
      const _Float16* tp = Th2 + (size_t)cj * FC + lane16 * NH;
      f16x8 tv0 = *reinterpret_cast<const f16x8*>(tp);
      f16x8 tv1 = *reinterpret_cast<const f16x8*>(tp + 128);
      f16x8 tv2 = *reinterpret_cast<const f16x8*>(tp + 256);
      f16x8 tv3 = *reinterpret_cast<const f16x8*>(tp + 384);
      #pragma unroll
      for (int h = 0; h < NH; ++h) {
        float e = __shfl(ex[h], gbase + j);
        facc[0][h] = fmaf(e, (float)tv0[h], facc[0][h]);
        facc[1][h] = fmaf(e, (float)tv1[h], facc[1][h]);
        facc[2][h] = fmaf(e, (float)tv2[h], facc[2][h]);
        facc[3][h] = fmaf(e, (float)tv3[h], facc[3][h]);
      }
    }
  }

  // reduce den across the 16-lane group
  #pragma unroll
  for (int h = 0; h < NH; ++h) {
    #pragma unroll
    for (int off = 1; off < 16; off <<= 1)
      dacc[h] += __shfl_xor(dacc[h], off);
  }

  float rden[NH];
  #pragma unroll
  for (int h = 0; h < NH; ++h) rden[h] = dacc[h] > 0.f ? 1.0f / dacc[h] : 0.f;

  // combine heads, add bias, relu; lane16 covers f = q*16 + lane16
  #pragma unroll
  for (int q = 0; q < 4; ++q) {
    const int f = q * 16 + lane16;
    float sb = 0.f;
    #pragma unroll
    for (int h = 0; h < NH; ++h) sb += b[h * FO + f];
    float v = 0.f;
    #pragma unroll
    for (int h = 0; h < NH; ++h) v += facc[q][h] * rden[h];
    v = (v + sb) * 0.125f;
    out[(size_t)r * FO + f] = v > 0.f ? v : 0.f;
  }
}

extern "C" void kernel_launch(void* const* d_in, const int* in_sizes, int n_in,
                              void* d_out, int out_size, void* d_ws, size_t ws_size,
                              hipStream_t stream) {
  const float* x    = (const float*)d_in[0];
  const float* W    = (const float*)d_in[1];
  const float* a    = (const float*)d_in[2];
  const float* b    = (const float*)d_in[3];
  const int*   rows = (const int*)d_in[4];
  const int*   cols = (const int*)d_in[5];
  const int N = in_sizes[0] / FI;
  const int E = in_sizes[4];

  char* p = (char*)d_ws;
  _Float16* Th2      = (_Float16*)p;  p += (size_t)N * FC * sizeof(_Float16);
  _Float16* Wth      = (_Float16*)p;  p += (size_t)NH * FO * FI * sizeof(_Float16);
  float*    aw       = (float*)p;     p += (size_t)N * NH * sizeof(float);
  int*      deg      = (int*)p;       p += (size_t)N * sizeof(int);
  int*      degcnt   = (int*)p;       p += NBIN * sizeof(int);   // zeroed with deg
  int*      row_start= (int*)p;       p += (size_t)(N + 4) * sizeof(int);
  int*      cursor   = (int*)p;       p += (size_t)N * sizeof(int);
  int*      colperm  = (int*)p;       p += (size_t)E * sizeof(int);
  int*      blocksums= (int*)p;       p += 64 * sizeof(int);
  int*      degoff   = (int*)p;       p += NBIN * sizeof(int);
  int*      row_order= (int*)p;       p += (size_t)N * sizeof(int);
  float*    out = (float*)d_out;

  const int nb = (N + 1023) / 1024;

  // CSR build + degree sort
  hipMemsetAsync(deg, 0, ((size_t)N + NBIN) * sizeof(int), stream); // deg+degcnt
  b1_hist<<<(E + 255) / 256, 256, 0, stream>>>(rows, deg, E);
  b2a_blocksum<<<nb, 256, 0, stream>>>(deg, blocksums, N);
  b2b_scanblocks<<<1, 64, 0, stream>>>(blocksums, nb, row_start, N, E);
  b2c_rescan<<<nb, 256, 0, stream>>>(deg, blocksums, row_start, cursor, degcnt, N);
  b3_scatter<<<(E + 255) / 256, 256, 0, stream>>>(rows, cols, cursor, colperm, E);
  b4_degscan<<<1, 64, 0, stream>>>(degcnt, degoff);
  b5_roworder<<<(N + 255) / 256, 256, 0, stream>>>(deg, degoff, row_order, N);

  // dense feature transform (all heads, fused transpose + aw)
  p1_wconv<<<(NH * FO * FI + 255) / 256, 256, 0, stream>>>(W, Wth);
  k1_v2<<<(N + BM - 1) / BM, 512, 0, stream>>>(x, Wth, a, Th2, aw, N);

  // fused edge pipeline (degree-sorted row assignment)
  k4_fused<<<(N + 15) / 16, 256, 0, stream>>>(row_start, colperm, row_order,
                                              aw, Th2, b, out, N);
}

// Round 10
// 303.219 us; speedup vs baseline: 1.4372x; 1.4372x over previous
//
#include <hip/hip_runtime.h>
#include <hip/hip_bf16.h>
#include <hip/hip_fp16.h>

// SparseGAT forward. fp16-MFMA feature transform (128-row tile, wave-per-head,
// fused transpose + aw); CSR edge pipeline, 16-lane-group rows assigned in
// DEGREE-SORTED order via hierarchical counting sort (LDS-atomic scatter).
// N=50000, FI=256, FO=64, H=8, E=800000, avg deg 16.
//
// Th2 [n][f*8+h] head-minor fp16 (1KB/row).
// ws: Th2[N*512]f16 | Wth[8*64*256]f16 | aw[N*8]f32 | deg[N] | row_start[N+4]
//     | cursor[N] | colperm[E] | blocksums[64] | row_order[N] | blockhist[64*nbp]

#define FI 256
#define FO 64
#define NH 8
#define FC 512
#define BM 128
#define NBIN 64

typedef _Float16 f16x8 __attribute__((ext_vector_type(8)));
typedef float f32x16 __attribute__((ext_vector_type(16)));
typedef float f32x8 __attribute__((ext_vector_type(8)));

// ---------------- P1: W[h][k][f] -> Wth[h][f][k] fp16 -----------------------
__global__ __launch_bounds__(256)
void p1_wconv(const float* __restrict__ W, _Float16* __restrict__ Wth) {
  int idx = blockIdx.x * 256 + threadIdx.x;   // h*64*256 + f*256 + k
  if (idx >= NH * FO * FI) return;
  int k = idx & (FI - 1);
  int f = (idx >> 8) & (FO - 1);
  int h = idx >> 14;
  Wth[idx] = (_Float16)W[((size_t)h * FI + k) * FO + f];
}

// ---------------- K1v2: 128-row tile, wave = head ---------------------------
__global__ __launch_bounds__(512)
void k1_v2(const float* __restrict__ x, const _Float16* __restrict__ Wth,
           const float* __restrict__ a, _Float16* __restrict__ Th2,
           float* __restrict__ aw, int N) {
  __shared__ _Float16 smem[BM * 136];            // 34.8 KB, aliased Xs / Tt
  auto Xs = reinterpret_cast<_Float16(*)[136]>(smem);   // [128][136]
  auto Tt = reinterpret_cast<_Float16(*)[512]>(smem);   // [32][512]
  const int bm = blockIdx.x * BM;
  const int t = threadIdx.x;
  const int w = t >> 6;             // wave id = head
  const int lane = t & 63;
  const int l31 = lane & 31;
  const int kh = (lane >> 5) * 8;
  const _Float16* Wh = Wth + (size_t)w * (FO * FI);

  f32x16 acc[4][2];
  #pragma unroll
  for (int mr = 0; mr < 4; ++mr)
    #pragma unroll
    for (int wc = 0; wc < 2; ++wc) acc[mr][wc] = (f32x16)0.0f;

  #pragma unroll
  for (int k0 = 0; k0 < 2; ++k0) {
    if (k0) __syncthreads();
    #pragma unroll
    for (int r = 0; r < 8; ++r) {
      int i = t + r * 512;          // 0..4095
      int row = i >> 5;             // 32 float4 per row
      int q = i & 31;
      float4 v = make_float4(0.f, 0.f, 0.f, 0.f);
      if (bm + row < N)
        v = reinterpret_cast<const float4*>(&x[(size_t)(bm + row) * FI + k0 * 128])[q];
      _Float16 o[4] = {(_Float16)v.x, (_Float16)v.y, (_Float16)v.z, (_Float16)v.w};
      *reinterpret_cast<uint2*>(&Xs[row][q * 4]) = *reinterpret_cast<uint2*>(o);
    }
    __syncthreads();
    #pragma unroll
    for (int kk = 0; kk < 8; ++kk) {
      f16x8 af[4], bf[2];
      #pragma unroll
      for (int mr = 0; mr < 4; ++mr)
        af[mr] = *reinterpret_cast<const f16x8*>(&Xs[mr * 32 + l31][kk * 16 + kh]);
      #pragma unroll
      for (int wc = 0; wc < 2; ++wc)
        bf[wc] = *reinterpret_cast<const f16x8*>(
            &Wh[(size_t)(wc * 32 + l31) * FI + k0 * 128 + kk * 16 + kh]);
      #pragma unroll
      for (int mr = 0; mr < 4; ++mr)
        #pragma unroll
        for (int wc = 0; wc < 2; ++wc)
          acc[mr][wc] =
              __builtin_amdgcn_mfma_f32_32x32x16_f16(af[mr], bf[wc], acc[mr][wc], 0, 0, 0);
    }
  }

  // aw[n][w] = sum_f T[n][w][f] * a[w][f]
  const float av0 = a[w * FO + l31], av1 = a[w * FO + 32 + l31];
  #pragma unroll
  for (int mr = 0; mr < 4; ++mr)
    #pragma unroll
    for (int reg = 0; reg < 16; ++reg) {
      float s = acc[mr][0][reg] * av0 + acc[mr][1][reg] * av1;
      #pragma unroll
      for (int off = 1; off < 32; off <<= 1) s += __shfl_xor(s, off);
      if (l31 == 0) {
        int rl = mr * 32 + (reg & 3) + 8 * (reg >> 2) + 4 * (lane >> 5);
        if (bm + rl < N) aw[(size_t)(bm + rl) * NH + w] = s;
      }
    }

  // Th2: transpose 32-row chunks through LDS, coalesced 16B stores
  #pragma unroll
  for (int ch = 0; ch < 4; ++ch) {
    __syncthreads();
    #pragma unroll
    for (int wc = 0; wc < 2; ++wc) {
      const int f = wc * 32 + l31;
      #pragma unroll
      for (int reg = 0; reg < 16; ++reg) {
        int rl = (reg & 3) + 8 * (reg >> 2) + 4 * (lane >> 5);
        Tt[rl][f * NH + w] = (_Float16)acc[ch][wc][reg];
      }
    }
    __syncthreads();
    #pragma unroll
    for (int r = 0; r < 4; ++r) {
      int i = t + r * 512;          // 0..2047
      int row = i >> 6, q = i & 63;
      int grow = bm + ch * 32 + row;
      if (grow < N)
        *reinterpret_cast<uint4*>(&Th2[(size_t)grow * FC + q * 8]) =
            *reinterpret_cast<const uint4*>(&Tt[row][q * 8]);
    }
  }
}

// ---------------- B1: degree histogram --------------------------------------
__global__ __launch_bounds__(256)
void b1_hist(const int* __restrict__ rows, int* __restrict__ deg, int E) {
  int e = blockIdx.x * 256 + threadIdx.x;
  if (e < E) atomicAdd(&deg[rows[e]], 1);
}

// ---------------- B2a: per-block sums (1024 elems/block) --------------------
__global__ __launch_bounds__(256)
void b2a_blocksum(const int* __restrict__ deg, int* __restrict__ blocksums, int N) {
  __shared__ int red[256];
  const int t = threadIdx.x;
  const int base = blockIdx.x * 1024 + t * 4;
  int s = 0;
  #pragma unroll
  for (int j = 0; j < 4; ++j) { int i = base + j; if (i < N) s += deg[i]; }
  red[t] = s;
  __syncthreads();
  for (int off = 128; off; off >>= 1) {
    if (t < off) red[t] += red[t + off];
    __syncthreads();
  }
  if (t == 0) blocksums[blockIdx.x] = red[0];
}

// ---------------- B2b: exclusive scan of block sums (1 wave) ----------------
__global__ __launch_bounds__(64)
void b2b_scanblocks(int* __restrict__ blocksums, int nb,
                    int* __restrict__ row_start, int N, int E) {
  const int lane = threadIdx.x;
  int carry = 0;
  for (int base = 0; base < nb; base += 64) {
    int i = base + lane;
    int v = (i < nb) ? blocksums[i] : 0;
    int inc = v;
    #pragma unroll
    for (int off = 1; off < 64; off <<= 1) {
      int t = __shfl_up(inc, off);
      if (lane >= off) inc += t;
    }
    if (i < nb) blocksums[i] = inc - v + carry;  // exclusive
    carry += __shfl(inc, 63);
  }
  if (lane == 0) row_start[N] = E;
}

// ---------------- B2c: per-block rescan -> row_start, cursor ----------------
__global__ __launch_bounds__(256)
void b2c_rescan(const int* __restrict__ deg, const int* __restrict__ blocksums,
                int* __restrict__ row_start, int* __restrict__ cursor, int N) {
  __shared__ int ts[256];
  const int t = threadIdx.x;
  const int base = blockIdx.x * 1024 + t * 4;
  int v[4]; int s = 0;
  #pragma unroll
  for (int j = 0; j < 4; ++j) { int i = base + j; v[j] = (i < N) ? deg[i] : 0; s += v[j]; }
  ts[t] = s;
  __syncthreads();
  for (int off = 1; off < 256; off <<= 1) {
    int add = (t >= off) ? ts[t - off] : 0;
    __syncthreads();
    ts[t] += add;
    __syncthreads();
  }
  int run = blocksums[blockIdx.x] + ts[t] - s;
  #pragma unroll
  for (int j = 0; j < 4; ++j) {
    int i = base + j;
    if (i < N) { row_start[i] = run; cursor[i] = run; run += v[j]; }
  }
}

// ---------------- B3: scatter cols into CSR order ---------------------------
__global__ __launch_bounds__(256)
void b3_scatter(const int* __restrict__ rows, const int* __restrict__ cols,
                int* __restrict__ cursor, int* __restrict__ colperm, int E) {
  int e = blockIdx.x * 256 + threadIdx.x;
  if (e >= E) return;
  int pos = atomicAdd(&cursor[rows[e]], 1);
  colperm[pos] = cols[e];
}

// ---------------- B5a: per-block degree histogram -> blockhist[bin][blk] ----
__global__ __launch_bounds__(256)
void b5a_hist(const int* __restrict__ deg, int* __restrict__ blockhist,
              int N, int nbp) {
  __shared__ int hist[NBIN];
  const int t = threadIdx.x;
  if (t < NBIN) hist[t] = 0;
  __syncthreads();
  const int base = blockIdx.x * 1024 + t * 4;
  #pragma unroll
  for (int j = 0; j < 4; ++j) {
    int i = base + j;
    if (i < N) atomicAdd(&hist[min(deg[i], NBIN - 1)], 1);
  }
  __syncthreads();
  if (t < NBIN) blockhist[t * nbp + blockIdx.x] = hist[t];
}

// ---------------- B5b: offsets (1 wave; lane = bin) -------------------------
// blockhist[bin][blk] (counts) -> running global offsets, in place.
__global__ __launch_bounds__(64)
void b5b_scan(int* __restrict__ blockhist, int nbp) {
  const int lane = threadIdx.x;     // bin
  int* rowp = blockhist + lane * nbp;
  int tot = 0;
  for (int c = 0; c < nbp / 4; ++c) {
    int4 v = reinterpret_cast<const int4*>(rowp)[c];
    tot += v.x + v.y + v.z + v.w;
  }
  // exclusive scan of bin totals across 64 lanes
  int inc = tot;
  #pragma unroll
  for (int off = 1; off < 64; off <<= 1) {
    int t = __shfl_up(inc, off);
    if (lane >= off) inc += t;
  }
  int run = inc - tot;              // global base of this bin
  for (int c = 0; c < nbp / 4; ++c) {
    int4 v = reinterpret_cast<const int4*>(rowp)[c];
    int4 o;
    o.x = run; run += v.x;
    o.y = run; run += v.y;
    o.z = run; run += v.z;
    o.w = run; run += v.w;
    reinterpret_cast<int4*>(rowp)[c] = o;
  }
}

// ---------------- B5c: scatter rows (LDS cursors only) ----------------------
__global__ __launch_bounds__(256)
void b5c_scatter(const int* __restrict__ deg, const int* __restrict__ blockhist,
                 int* __restrict__ row_order, int N, int nbp) {
  __shared__ int cur[NBIN];
  const int t = threadIdx.x;
  if (t < NBIN) cur[t] = blockhist[t * nbp + blockIdx.x];
  __syncthreads();
  const int base = blockIdx.x * 1024 + t * 4;
  #pragma unroll
  for (int j = 0; j < 4; ++j) {
    int i = base + j;
    if (i < N) {
      int pos = atomicAdd(&cur[min(deg[i], NBIN - 1)], 1);
      row_order[pos] = i;
    }
  }
}

// ---------------- K4: fused softmax + aggregation, row per 16-lane group ----
// Rows in degree-sorted order: groups in a wave have ~equal trip counts.
__global__ __launch_bounds__(256)
void k4_fused(const int* __restrict__ row_start, const int* __restrict__ colperm,
              const int* __restrict__ row_order,
              const float* __restrict__ aw, const _Float16* __restrict__ Th2,
              const float* __restrict__ b, float* __restrict__ out, int N) {
  const int lane16 = threadIdx.x & 15;
  const int gbase  = threadIdx.x & 48;       // group base lane within wave
  const int ri = blockIdx.x * 16 + (threadIdx.x >> 4);
  if (ri >= N) return;
  const int r = row_order[ri];

  const int s0 = row_start[r], s1 = row_start[r + 1];
  f32x8 awr = *reinterpret_cast<const f32x8*>(&aw[(size_t)r * NH]);

  float facc[4][NH] = {};
  float dacc[NH] = {};

  for (int base = s0; base < s1; base += 16) {
    const int mm = min(16, s1 - base);
    const bool valid = lane16 < mm;
    int c_l = valid ? colperm[base + lane16] : 0;

    // lane-parallel ex over this group's <=16 edges
    f32x8 awc = *reinterpret_cast<const f32x8*>(&aw[(size_t)c_l * NH]);
    float ex[NH];
    #pragma unroll
    for (int h = 0; h < NH; ++h) {
      float s = awr[h] + awc[h];
      float lr = s > 0.f ? s : 0.2f * s;
      ex[h] = valid ? __expf(lr) : 0.f;
      dacc[h] += ex[h];
    }

    // serial gather: per edge, 4 independent quarter-row loads
    for (int j = 0; j < mm; ++j) {
      int cj = __shfl(c_l, gbase + j);
      const _Float16* tp = Th2 + (size_t)cj * FC + lane16 * NH;
      f16x8 tv0 = *reinterpret_cast<const f16x8*>(tp);
      f16x8 tv1 = *reinterpret_cast<const f16x8*>(tp + 128);
      f16x8 tv2 = *reinterpret_cast<const f16x8*>(tp + 256);
      f16x8 tv3 = *reinterpret_cast<const f16x8*>(tp + 384);
      #pragma unroll
      for (int h = 0; h < NH; ++h) {
        float e = __shfl(ex[h], gbase + j);
        facc[0][h] = fmaf(e, (float)tv0[h], facc[0][h]);
        facc[1][h] = fmaf(e, (float)tv1[h], facc[1][h]);
        facc[2][h] = fmaf(e, (float)tv2[h], facc[2][h]);
        facc[3][h] = fmaf(e, (float)tv3[h], facc[3][h]);
      }
    }
  }

  // reduce den across the 16-lane group
  #pragma unroll
  for (int h = 0; h < NH; ++h) {
    #pragma unroll
    for (int off = 1; off < 16; off <<= 1)
      dacc[h] += __shfl_xor(dacc[h], off);
  }

  float rden[NH];
  #pragma unroll
  for (int h = 0; h < NH; ++h) rden[h] = dacc[h] > 0.f ? 1.0f / dacc[h] : 0.f;

  // combine heads, add bias, relu; lane16 covers f = q*16 + lane16
  #pragma unroll
  for (int q = 0; q < 4; ++q) {
    const int f = q * 16 + lane16;
    float sb = 0.f;
    #pragma unroll
    for (int h = 0; h < NH; ++h) sb += b[h * FO + f];
    float v = 0.f;
    #pragma unroll
    for (int h = 0; h < NH; ++h) v += facc[q][h] * rden[h];
    v = (v + sb) * 0.125f;
    out[(size_t)r * FO + f] = v > 0.f ? v : 0.f;
  }
}

extern "C" void kernel_launch(void* const* d_in, const int* in_sizes, int n_in,
                              void* d_out, int out_size, void* d_ws, size_t ws_size,
                              hipStream_t stream) {
  const float* x    = (const float*)d_in[0];
  const float* W    = (const float*)d_in[1];
  const float* a    = (const float*)d_in[2];
  const float* b    = (const float*)d_in[3];
  const int*   rows = (const int*)d_in[4];
  const int*   cols = (const int*)d_in[5];
  const int N = in_sizes[0] / FI;
  const int E = in_sizes[4];

  const int nb  = (N + 1023) / 1024;        // 1024-row blocks
  const int nbp = ((nb + 3) / 4) * 4;       // padded for int4 in b5b

  char* p = (char*)d_ws;
  _Float16* Th2      = (_Float16*)p;  p += (size_t)N * FC * sizeof(_Float16);
  _Float16* Wth      = (_Float16*)p;  p += (size_t)NH * FO * FI * sizeof(_Float16);
  float*    aw       = (float*)p;     p += (size_t)N * NH * sizeof(float);
  int*      deg      = (int*)p;       p += (size_t)N * sizeof(int);
  int*      row_start= (int*)p;       p += (size_t)(N + 4) * sizeof(int);
  int*      cursor   = (int*)p;       p += (size_t)N * sizeof(int);
  int*      colperm  = (int*)p;       p += (size_t)E * sizeof(int);
  int*      blocksums= (int*)p;       p += 64 * sizeof(int);
  int*      row_order= (int*)p;       p += (size_t)N * sizeof(int);
  int*      blockhist= (int*)p;       p += (size_t)NBIN * nbp * sizeof(int);
  float*    out = (float*)d_out;

  // CSR build
  hipMemsetAsync(deg, 0, (size_t)N * sizeof(int), stream);
  hipMemsetAsync(blockhist, 0, (size_t)NBIN * nbp * sizeof(int), stream);
  b1_hist<<<(E + 255) / 256, 256, 0, stream>>>(rows, deg, E);
  b2a_blocksum<<<nb, 256, 0, stream>>>(deg, blocksums, N);
  b2b_scanblocks<<<1, 64, 0, stream>>>(blocksums, nb, row_start, N, E);
  b2c_rescan<<<nb, 256, 0, stream>>>(deg, blocksums, row_start, cursor, N);
  b3_scatter<<<(E + 255) / 256, 256, 0, stream>>>(rows, cols, cursor, colperm, E);

  // degree sort (hierarchical counting sort, LDS atomics only)
  b5a_hist<<<nb, 256, 0, stream>>>(deg, blockhist, N, nbp);
  b5b_scan<<<1, 64, 0, stream>>>(blockhist, nbp);
  b5c_scatter<<<nb, 256, 0, stream>>>(deg, blockhist, row_order, N, nbp);

  // dense feature transform (all heads, fused transpose + aw)
  p1_wconv<<<(NH * FO * FI + 255) / 256, 256, 0, stream>>>(W, Wth);
  k1_v2<<<(N + BM - 1) / BM, 512, 0, stream>>>(x, Wth, a, Th2, aw, N);

  // fused edge pipeline (degree-sorted row assignment)
  k4_fused<<<(N + 15) / 16, 256, 0, stream>>>(row_start, colperm, row_order,
                                              aw, Th2, b, out, N);
}

// Round 11
// 285.205 us; speedup vs baseline: 1.5280x; 1.0632x over previous
//
#include <hip/hip_runtime.h>
#include <hip/hip_bf16.h>
#include <hip/hip_fp16.h>

// SparseGAT forward. fp16-MFMA feature transform with SWAPPED operands
// (D[f][node]: lane=node, regs=f -> direct register->global Th stores, no LDS
// transpose, 1-shfl aw). CSR edge pipeline, 16-lane-group rows, degree-sorted.
// N=50000, FI=256, FO=64, H=8, E=800000, avg deg 16.
//
// Th [n][h*64+f] head-major fp16 (1KB/row); k4 group reads whole row, layout-agnostic.
// ws: Th[N*512]f16 | Wth[8*64*256]f16 | aw[N*8]f32 | deg[N] | row_start[N+4]
//     | cursor[N] | colperm[E] | blocksums[64] | row_order[N] | blockhist[64*nbp]

#define FI 256
#define FO 64
#define NH 8
#define FC 512
#define BM 128
#define NBIN 64

typedef _Float16 f16x8 __attribute__((ext_vector_type(8)));
typedef float f32x16 __attribute__((ext_vector_type(16)));
typedef float f32x8 __attribute__((ext_vector_type(8)));

// ---------------- P1: W[h][k][f] -> Wth[h][f][k] fp16 -----------------------
__global__ __launch_bounds__(256)
void p1_wconv(const float* __restrict__ W, _Float16* __restrict__ Wth) {
  int idx = blockIdx.x * 256 + threadIdx.x;   // h*64*256 + f*256 + k
  if (idx >= NH * FO * FI) return;
  int k = idx & (FI - 1);
  int f = (idx >> 8) & (FO - 1);
  int h = idx >> 14;
  Wth[idx] = (_Float16)W[((size_t)h * FI + k) * FO + f];
}

// ---------------- K1v3: swapped-operand MFMA, direct stores ------------------
// 512 threads = 8 waves; wave w = head w. mfma(W-frag, x-frag, acc) gives
// D[f][node]: col(lane&31)=node, row(reg)=f. Lane owns 4 nodes (mr) x 32 f.
__global__ __launch_bounds__(512)
void k1_v3(const float* __restrict__ x, const _Float16* __restrict__ Wth,
           const float* __restrict__ a, _Float16* __restrict__ Th,
           float* __restrict__ aw, int N) {
  __shared__ _Float16 Xs[BM][136];   // 34.8 KB; +8 pad
  const int bm = blockIdx.x * BM;
  const int t = threadIdx.x;
  const int w = t >> 6;             // wave id = head
  const int lane = t & 63;
  const int l31 = lane & 31;
  const int hi = lane >> 5;
  const int kh = hi * 8;
  const _Float16* Wh = Wth + (size_t)w * (FO * FI);

  f32x16 acc[4][2];
  #pragma unroll
  for (int mr = 0; mr < 4; ++mr)
    #pragma unroll
    for (int wc = 0; wc < 2; ++wc) acc[mr][wc] = (f32x16)0.0f;

  #pragma unroll
  for (int k0 = 0; k0 < 2; ++k0) {
    if (k0) __syncthreads();
    // stage 128x128 fp16 chunk
    #pragma unroll
    for (int r = 0; r < 8; ++r) {
      int i = t + r * 512;          // 0..4095
      int row = i >> 5;             // 32 float4 per row
      int q = i & 31;
      float4 v = make_float4(0.f, 0.f, 0.f, 0.f);
      if (bm + row < N)
        v = reinterpret_cast<const float4*>(&x[(size_t)(bm + row) * FI + k0 * 128])[q];
      _Float16 o[4] = {(_Float16)v.x, (_Float16)v.y, (_Float16)v.z, (_Float16)v.w};
      *reinterpret_cast<uint2*>(&Xs[row][q * 4]) = *reinterpret_cast<uint2*>(o);
    }
    __syncthreads();
    #pragma unroll
    for (int kk = 0; kk < 8; ++kk) {
      f16x8 xf[4], wf[2];
      #pragma unroll
      for (int mr = 0; mr < 4; ++mr)
        xf[mr] = *reinterpret_cast<const f16x8*>(&Xs[mr * 32 + l31][kk * 16 + kh]);
      #pragma unroll
      for (int wc = 0; wc < 2; ++wc)
        wf[wc] = *reinterpret_cast<const f16x8*>(
            &Wh[(size_t)(wc * 32 + l31) * FI + k0 * 128 + kk * 16 + kh]);
      // SWAPPED: A=W-frag (i=f), B=x-frag (j=node) -> D[f][node]
      #pragma unroll
      for (int mr = 0; mr < 4; ++mr)
        #pragma unroll
        for (int wc = 0; wc < 2; ++wc)
          acc[mr][wc] =
              __builtin_amdgcn_mfma_f32_32x32x16_f16(wf[wc], xf[mr], acc[mr][wc], 0, 0, 0);
    }
  }

  // acc[mr][wc][reg] = T[n=bm+mr*32+l31][w*64 + wc*32 + (reg&3)+8*(reg>>2)+4*hi]

  // aw: per-lane dot over its 32 f, combine lane-halves with one shfl
  float s4[4] = {0.f, 0.f, 0.f, 0.f};
  #pragma unroll
  for (int wc = 0; wc < 2; ++wc)
    #pragma unroll
    for (int reg = 0; reg < 16; ++reg) {
      float av = a[w * FO + wc * 32 + (reg & 3) + 8 * (reg >> 2) + 4 * hi];
      #pragma unroll
      for (int mr = 0; mr < 4; ++mr)
        s4[mr] = fmaf(acc[mr][wc][reg], av, s4[mr]);
    }
  #pragma unroll
  for (int mr = 0; mr < 4; ++mr) {
    float s = s4[mr] + __shfl_xor(s4[mr], 32);
    int n = bm + mr * 32 + l31;
    if (hi == 0 && n < N) aw[(size_t)n * NH + w] = s;
  }

  // direct stores: per (mr,wc,quad g): 4 consecutive f -> 8B store
  #pragma unroll
  for (int mr = 0; mr < 4; ++mr) {
    int n = bm + mr * 32 + l31;
    if (n >= N) continue;
    _Float16* rowp = Th + (size_t)n * FC + w * FO;
    #pragma unroll
    for (int wc = 0; wc < 2; ++wc)
      #pragma unroll
      for (int g = 0; g < 4; ++g) {
        _Float16 o[4] = {(_Float16)acc[mr][wc][4 * g + 0],
                         (_Float16)acc[mr][wc][4 * g + 1],
                         (_Float16)acc[mr][wc][4 * g + 2],
                         (_Float16)acc[mr][wc][4 * g + 3]};
        *reinterpret_cast<uint2*>(&rowp[wc * 32 + 8 * g + 4 * hi]) =
            *reinterpret_cast<uint2*>(o);
      }
  }
}

// ---------------- B1: degree histogram --------------------------------------
__global__ __launch_bounds__(256)
void b1_hist(const int* __restrict__ rows, int* __restrict__ deg, int E) {
  int e = blockIdx.x * 256 + threadIdx.x;
  if (e < E) atomicAdd(&deg[rows[e]], 1);
}

// ---------------- B2a: per-block sums (1024 elems/block) --------------------
__global__ __launch_bounds__(256)
void b2a_blocksum(const int* __restrict__ deg, int* __restrict__ blocksums, int N) {
  __shared__ int red[256];
  const int t = threadIdx.x;
  const int base = blockIdx.x * 1024 + t * 4;
  int s = 0;
  #pragma unroll
  for (int j = 0; j < 4; ++j) { int i = base + j; if (i < N) s += deg[i]; }
  red[t] = s;
  __syncthreads();
  for (int off = 128; off; off >>= 1) {
    if (t < off) red[t] += red[t + off];
    __syncthreads();
  }
  if (t == 0) blocksums[blockIdx.x] = red[0];
}

// ---------------- B2b: exclusive scan of block sums (1 wave) ----------------
__global__ __launch_bounds__(64)
void b2b_scanblocks(int* __restrict__ blocksums, int nb,
                    int* __restrict__ row_start, int N, int E) {
  const int lane = threadIdx.x;
  int carry = 0;
  for (int base = 0; base < nb; base += 64) {
    int i = base + lane;
    int v = (i < nb) ? blocksums[i] : 0;
    int inc = v;
    #pragma unroll
    for (int off = 1; off < 64; off <<= 1) {
      int t = __shfl_up(inc, off);
      if (lane >= off) inc += t;
    }
    if (i < nb) blocksums[i] = inc - v + carry;  // exclusive
    carry += __shfl(inc, 63);
  }
  if (lane == 0) row_start[N] = E;
}

// ---------------- B2c: rescan -> row_start, cursor; + per-block deg hist ----
__global__ __launch_bounds__(256)
void b2c_rescan(const int* __restrict__ deg, const int* __restrict__ blocksums,
                int* __restrict__ row_start, int* __restrict__ cursor,
                int* __restrict__ blockhist, int N, int nbp) {
  __shared__ int ts[256];
  __shared__ int hist[NBIN];
  const int t = threadIdx.x;
  const int base = blockIdx.x * 1024 + t * 4;
  if (t < NBIN) hist[t] = 0;
  int v[4]; int s = 0;
  #pragma unroll
  for (int j = 0; j < 4; ++j) { int i = base + j; v[j] = (i < N) ? deg[i] : 0; s += v[j]; }
  ts[t] = s;
  __syncthreads();
  for (int off = 1; off < 256; off <<= 1) {
    int add = (t >= off) ? ts[t - off] : 0;
    __syncthreads();
    ts[t] += add;
    __syncthreads();
  }
  int run = blocksums[blockIdx.x] + ts[t] - s;
  #pragma unroll
  for (int j = 0; j < 4; ++j) {
    int i = base + j;
    if (i < N) {
      row_start[i] = run; cursor[i] = run; run += v[j];
      atomicAdd(&hist[min(v[j], NBIN - 1)], 1);
    }
  }
  __syncthreads();
  if (t < NBIN) blockhist[t * nbp + blockIdx.x] = hist[t];
}

// ---------------- B3: scatter cols into CSR order ---------------------------
__global__ __launch_bounds__(256)
void b3_scatter(const int* __restrict__ rows, const int* __restrict__ cols,
                int* __restrict__ cursor, int* __restrict__ colperm, int E) {
  int e = blockIdx.x * 256 + threadIdx.x;
  if (e >= E) return;
  int pos = atomicAdd(&cursor[rows[e]], 1);
  colperm[pos] = cols[e];
}

// ---------------- B5b: bin offsets (1 wave; lane = bin) ---------------------
__global__ __launch_bounds__(64)
void b5b_scan(int* __restrict__ blockhist, int nbp) {
  const int lane = threadIdx.x;     // bin
  int* rowp = blockhist + lane * nbp;
  int tot = 0;
  for (int c = 0; c < nbp / 4; ++c) {
    int4 v = reinterpret_cast<const int4*>(rowp)[c];
    tot += v.x + v.y + v.z + v.w;
  }
  int inc = tot;
  #pragma unroll
  for (int off = 1; off < 64; off <<= 1) {
    int t = __shfl_up(inc, off);
    if (lane >= off) inc += t;
  }
  int run = inc - tot;              // global base of this bin
  for (int c = 0; c < nbp / 4; ++c) {
    int4 v = reinterpret_cast<const int4*>(rowp)[c];
    int4 o;
    o.x = run; run += v.x;
    o.y = run; run += v.y;
    o.z = run; run += v.z;
    o.w = run; run += v.w;
    reinterpret_cast<int4*>(rowp)[c] = o;
  }
}

// ---------------- B5c: scatter rows (LDS cursors only) ----------------------
__global__ __launch_bounds__(256)
void b5c_scatter(const int* __restrict__ deg, const int* __restrict__ blockhist,
                 int* __restrict__ row_order, int N, int nbp) {
  __shared__ int cur[NBIN];
  const int t = threadIdx.x;
  if (t < NBIN) cur[t] = blockhist[t * nbp + blockIdx.x];
  __syncthreads();
  const int base = blockIdx.x * 1024 + t * 4;
  #pragma unroll
  for (int j = 0; j < 4; ++j) {
    int i = base + j;
    if (i < N) {
      int pos = atomicAdd(&cur[min(deg[i], NBIN - 1)], 1);
      row_order[pos] = i;
    }
  }
}

// ---------------- K4: fused softmax + aggregation, head-major Th ------------
// 16-lane group per row (degree-sorted). Lane's 16B chunk q = (head 2q+hi8,
// f = (lane16&7)*8..+8). ex broadcast as packed half2 (4 shfl/edge);
// parity fix-up (xor 8) at row end.
__global__ __launch_bounds__(256)
void k4_fused(const int* __restrict__ row_start, const int* __restrict__ colperm,
              const int* __restrict__ row_order,
              const float* __restrict__ aw, const _Float16* __restrict__ Th,
              const float* __restrict__ b, float* __restrict__ out, int N) {
  const int lane16 = threadIdx.x & 15;
  const int gbase  = threadIdx.x & 48;       // group base lane within wave
  const int hi8    = lane16 >> 3;            // head parity of this lane
  const int ri = blockIdx.x * 16 + (threadIdx.x >> 4);
  if (ri >= N) return;
  const int r = row_order[ri];

  const int s0 = row_start[r], s1 = row_start[r + 1];
  f32x8 awr = *reinterpret_cast<const f32x8*>(&aw[(size_t)r * NH]);

  float facc[4][8] = {};
  float dacc[NH] = {};

  for (int base = s0; base < s1; base += 16) {
    const int mm = min(16, s1 - base);
    const bool valid = lane16 < mm;
    int c_l = valid ? colperm[base + lane16] : 0;

    // lane-parallel ex over this group's <=16 edges; pack pairs as half2
    f32x8 awc = *reinterpret_cast<const f32x8*>(&aw[(size_t)c_l * NH]);
    float ex[NH];
    int pkv[4];
    #pragma unroll
    for (int h = 0; h < NH; ++h) {
      float s = awr[h] + awc[h];
      float lr = s > 0.f ? s : 0.2f * s;
      ex[h] = valid ? __expf(lr) : 0.f;
      dacc[h] += ex[h];
    }
    #pragma unroll
    for (int q = 0; q < 4; ++q) {
      __half2 h2 = __floats2half2_rn(ex[2 * q], ex[2 * q + 1]);
      pkv[q] = *reinterpret_cast<int*>(&h2);
    }

    // serial gather: per edge, 4 independent 16B loads + 4 packed shfl
    for (int j = 0; j < mm; ++j) {
      int cj = __shfl(c_l, gbase + j);
      const _Float16* tp = Th + (size_t)cj * FC + lane16 * 8;
      f16x8 tv0 = *reinterpret_cast<const f16x8*>(tp);
      f16x8 tv1 = *reinterpret_cast<const f16x8*>(tp + 128);
      f16x8 tv2 = *reinterpret_cast<const f16x8*>(tp + 256);
      f16x8 tv3 = *reinterpret_cast<const f16x8*>(tp + 384);
      float eq[4];
      #pragma unroll
      for (int q = 0; q < 4; ++q) {
        int p = __shfl(pkv[q], gbase + j);
        float2 f2 = __half22float2(*reinterpret_cast<__half2*>(&p));
        eq[q] = hi8 ? f2.y : f2.x;
      }
      #pragma unroll
      for (int e = 0; e < 8; ++e) {
        facc[0][e] = fmaf(eq[0], (float)tv0[e], facc[0][e]);
        facc[1][e] = fmaf(eq[1], (float)tv1[e], facc[1][e]);
        facc[2][e] = fmaf(eq[2], (float)tv2[e], facc[2][e]);
        facc[3][e] = fmaf(eq[3], (float)tv3[e], facc[3][e]);
      }
    }
  }

  // reduce den across the 16-lane group
  #pragma unroll
  for (int h = 0; h < NH; ++h) {
    #pragma unroll
    for (int off = 1; off < 16; off <<= 1)
      dacc[h] += __shfl_xor(dacc[h], off);
  }
  float rden[NH];
  #pragma unroll
  for (int h = 0; h < NH; ++h) rden[h] = dacc[h] > 0.f ? 1.0f / dacc[h] : 0.f;

  // s[e] = sum_q facc[q][e] * rden[2q+hi8]; add parity partner (xor 8)
  float s[8] = {};
  #pragma unroll
  for (int q = 0; q < 4; ++q) {
    float rd = hi8 ? rden[2 * q + 1] : rden[2 * q];
    #pragma unroll
    for (int e = 0; e < 8; ++e) s[e] = fmaf(facc[q][e], rd, s[e]);
  }
  #pragma unroll
  for (int e = 0; e < 8; ++e) s[e] += __shfl_xor(s[e], 8);

  // lanes 0-7 hold f-group lane16*8..+8: bias, relu, write 32B each
  if (lane16 < 8) {
    #pragma unroll
    for (int e = 0; e < 8; ++e) {
      const int f = lane16 * 8 + e;
      float sb = 0.f;
      #pragma unroll
      for (int h = 0; h < NH; ++h) sb += b[h * FO + f];
      float v = (s[e] + sb) * 0.125f;
      out[(size_t)r * FO + f] = v > 0.f ? v : 0.f;
    }
  }
}

extern "C" void kernel_launch(void* const* d_in, const int* in_sizes, int n_in,
                              void* d_out, int out_size, void* d_ws, size_t ws_size,
                              hipStream_t stream) {
  const float* x    = (const float*)d_in[0];
  const float* W    = (const float*)d_in[1];
  const float* a    = (const float*)d_in[2];
  const float* b    = (const float*)d_in[3];
  const int*   rows = (const int*)d_in[4];
  const int*   cols = (const int*)d_in[5];
  const int N = in_sizes[0] / FI;
  const int E = in_sizes[4];

  const int nb  = (N + 1023) / 1024;        // 1024-row blocks
  const int nbp = ((nb + 3) / 4) * 4;       // padded for int4 in b5b

  char* p = (char*)d_ws;
  _Float16* Th       = (_Float16*)p;  p += (size_t)N * FC * sizeof(_Float16);
  _Float16* Wth      = (_Float16*)p;  p += (size_t)NH * FO * FI * sizeof(_Float16);
  float*    aw       = (float*)p;     p += (size_t)N * NH * sizeof(float);
  int*      deg      = (int*)p;       p += (size_t)N * sizeof(int);
  int*      row_start= (int*)p;       p += (size_t)(N + 4) * sizeof(int);
  int*      cursor   = (int*)p;       p += (size_t)N * sizeof(int);
  int*      colperm  = (int*)p;       p += (size_t)E * sizeof(int);
  int*      blocksums= (int*)p;       p += 64 * sizeof(int);
  int*      row_order= (int*)p;       p += (size_t)N * sizeof(int);
  int*      blockhist= (int*)p;       p += (size_t)NBIN * nbp * sizeof(int);
  float*    out = (float*)d_out;

  // CSR build + degree sort
  hipMemsetAsync(deg, 0, (size_t)N * sizeof(int), stream);
  hipMemsetAsync(blockhist, 0, (size_t)NBIN * nbp * sizeof(int), stream);
  b1_hist<<<(E + 255) / 256, 256, 0, stream>>>(rows, deg, E);
  b2a_blocksum<<<nb, 256, 0, stream>>>(deg, blocksums, N);
  b2b_scanblocks<<<1, 64, 0, stream>>>(blocksums, nb, row_start, N, E);
  b2c_rescan<<<nb, 256, 0, stream>>>(deg, blocksums, row_start, cursor,
                                     blockhist, N, nbp);
  b3_scatter<<<(E + 255) / 256, 256, 0, stream>>>(rows, cols, cursor, colperm, E);
  b5b_scan<<<1, 64, 0, stream>>>(blockhist, nbp);
  b5c_scatter<<<nb, 256, 0, stream>>>(deg, blockhist, row_order, N, nbp);

  // dense feature transform (swapped-operand MFMA, direct stores)
  p1_wconv<<<(NH * FO * FI + 255) / 256, 256, 0, stream>>>(W, Wth);
  k1_v3<<<(N + BM - 1) / BM, 512, 0, stream>>>(x, Wth, a, Th, aw, N);

  // fused edge pipeline (degree-sorted row assignment)
  k4_fused<<<(N + 15) / 16, 256, 0, stream>>>(row_start, colperm, row_order,
                                              aw, Th, b, out, N);
}